// Round 1
// baseline (9.685 us; speedup 1.0000x reference)
//
#include <hip/hip_runtime.h>
#include <math.h>

// Problem constants (match reference).
constexpr int Bn = 1024;   // batch
constexpr int Fn = 512;    // features
constexpr int Kn = 16;     // factor dim
constexpr int CSTRIDE = 520;  // column-copy row stride (pad: 8k bank offset across k)

// p2[b] = sum_k sum_j R[k,j] * T_k(j)
//   WX[f,k]   = x[b,f] * W[f,k]
//   R[k,j]    = WX[32k + (j>>4)][j&15]         (the reshape-not-transpose)
//   T_k(j)    = sum_{f>=j} WX[f,k]             (tril sum -> suffix sums)
// With j = 16q + r:  R-row k segment q == WX row f = 32k+q (register-resident),
//   T_k(16q+r) = Tq_k(q+1) + S_k(q,r)
//   Tq_k(m)    = sum_{f>=16m} WX[f,k]   (coarse suffix, 32-lane shuffle scan)
//   S_k(q,r)   = sum_{r'=r}^{15} WX[16q+r'][k]  (register suffix over col[16])
__global__ __launch_bounds__(512) void fm_kernel(
    const float* __restrict__ x,      // (B,F)
    const float* __restrict__ W,      // (F,K)
    const float* __restrict__ lin_w,  // (1,F)
    const float* __restrict__ lin_b,  // (1,)
    float* __restrict__ out)          // (B,1)
{
    const int b = blockIdx.x;
    const int t = threadIdx.x;   // == f, the WX row this thread owns
    const int k = t >> 5;        // column this thread consumes
    const int q = t & 31;        // coarse block index

    __shared__ float WXc[Kn * CSTRIDE];  // column-major swizzled copy: WXc[k][swz(f)] = WX[f][k]
    __shared__ float red[8];

    const float xv = x[(size_t)b * Fn + t];

    // W row f: 16 contiguous floats, 4x float4 (L2-resident after first blocks).
    const float4* Wrow = reinterpret_cast<const float4*>(W + (size_t)t * Kn);
    const float4 w0 = Wrow[0], w1 = Wrow[1], w2 = Wrow[2], w3 = Wrow[3];

    float row[16] = {xv*w0.x, xv*w0.y, xv*w0.z, xv*w0.w,
                     xv*w1.x, xv*w1.y, xv*w1.z, xv*w1.w,
                     xv*w2.x, xv*w2.y, xv*w2.z, xv*w2.w,
                     xv*w3.x, xv*w3.y, xv*w3.z, xv*w3.w};

    // XOR-swizzle: stride-32-float column accesses would be 16-way bank
    // conflicts; f ^ (f>>5) spreads the 32 q-values across all 32 banks.
    const int fs = t ^ (t >> 5);
    #pragma unroll
    for (int kk = 0; kk < Kn; ++kk)
        WXc[kk * CSTRIDE + fs] = row[kk];

    __syncthreads();

    // col[r] = WX[16q + r][k], conflict-free via swizzle (proof: low5 of
    // swz(16q+r) = 16(q&1) + (r ^ (q>>1)) -> distinct across the 32 q's).
    float col[16];
    const int base = k * CSTRIDE;
    #pragma unroll
    for (int r = 0; r < 16; ++r) {
        const int u = (q << 4) + r;
        col[r] = WXc[base + (u ^ (u >> 5))];
    }

    // Coarse block sum G_k[q] and 32-lane inclusive suffix scan over q.
    float G = 0.f;
    #pragma unroll
    for (int r = 0; r < 16; ++r) G += col[r];

    float incl = G;   // incl(q) = sum_{m>=q} G_k[m]
    #pragma unroll
    for (int d = 1; d < 32; d <<= 1) {
        const float o = __shfl_down(incl, d, 32);
        if (q + d < 32) incl += o;
    }
    const float Tq = incl - G;   // Tq_k(q+1)

    // Register-only suffix dot: acc += row[r] * (Tq + S_k(q,r)), r = 15..0.
    float S = 0.f, acc = 0.f;
    #pragma unroll
    for (int r = 15; r >= 0; --r) {
        S += col[r];
        acc = fmaf(row[r], Tq + S, acc);
    }

    // Linear-term partial: p1 = sum_f x[f]*lin_w[f].
    acc = fmaf(xv, lin_w[t], acc);

    // Block reduction: wave64 butterfly, then 8 partials through LDS.
    #pragma unroll
    for (int d = 32; d >= 1; d >>= 1)
        acc += __shfl_xor(acc, d);

    if ((t & 63) == 0) red[t >> 6] = acc;
    __syncthreads();
    if (t == 0) {
        float tot = red[0] + red[1] + red[2] + red[3]
                  + red[4] + red[5] + red[6] + red[7];
        tot += lin_b[0];
        out[b] = 1.0f / (1.0f + expf(-tot));
    }
}

extern "C" void kernel_launch(void* const* d_in, const int* in_sizes, int n_in,
                              void* d_out, int out_size, void* d_ws, size_t ws_size,
                              hipStream_t stream) {
    const float* x     = (const float*)d_in[0];
    const float* W     = (const float*)d_in[1];
    const float* lin_w = (const float*)d_in[2];
    const float* lin_b = (const float*)d_in[3];
    float* out = (float*)d_out;

    hipLaunchKernelGGL(fm_kernel, dim3(Bn), dim3(512), 0, stream,
                       x, W, lin_w, lin_b, out);
}